// Round 1
// baseline (12.783 us; speedup 1.0000x reference)
//
#include <hip/hip_runtime.h>

// Problem geometry (fixed by the reference module config)
#define IC    8
#define OC    16
#define H     32
#define W     32
#define PH    34
#define PW    34
#define OH    32
#define OW    32
#define BATCH 64
#define WCOLS (IC * PH * PW)   // 9248 columns of the Toeplitz weight
#define XSTR  35               // LDS row stride (floats): odd -> uniform 2-way bank alias (free)
#define PLANE (PH * XSTR)      // 34*35 = 1190 floats per input-channel plane

// One block per (batch, oc) pair; 256 threads; each thread computes a 1x4 output strip.
__global__ __launch_bounds__(256) void conv_toeplitz_kernel(
    const float* __restrict__ x,       // [B, IC*H*W]
    const float* __restrict__ weight,  // [OC*OH*OW, WCOLS] Toeplitz
    const float* __restrict__ bias,    // [OC*OH*OW]
    float* __restrict__ out)           // [B, OC*OH*OW]
{
    __shared__ float wk[IC * 9];        // this block's oc kernel slice
    __shared__ float xs[IC * PLANE];    // zero-padded input planes

    const int tid = threadIdx.x;
    const int blk = blockIdx.x;
    const int b   = blk >> 4;           // batch index
    const int oc  = blk & 15;           // output channel

    // --- recover conv kernel from the Toeplitz row for output (oc, oh=0, ow=0) ---
    if (tid < IC * 9) {
        const int ic = tid / 9;
        const int k  = tid - ic * 9;
        const int kh = k / 3;
        const int kw = k - kh * 3;
        wk[tid] = weight[(size_t)(oc * OH * OW) * WCOLS + (ic * PH + kh) * PW + kw];
    }

    // --- zero the padded LDS tile (borders must be 0) ---
    for (int i = tid; i < IC * PLANE; i += 256) xs[i] = 0.0f;
    __syncthreads();

    // --- stage x[b] into the interior of the padded LDS tile (coalesced float4 loads) ---
    const float4* xg = (const float4*)(x + (size_t)b * (IC * H * W));
    #pragma unroll
    for (int i = 0; i < 8; ++i) {
        const int k   = tid + i * 256;      // float4 index, 0..2047
        const float4 v = xg[k];
        const int ic  = k >> 8;             // 256 float4 per channel plane
        const int rem = k & 255;
        const int h   = rem >> 3;           // 8 float4 per row
        const int w4  = (rem & 7) << 2;
        float* dst = &xs[ic * PLANE + (h + 1) * XSTR + (w4 + 1)];
        dst[0] = v.x; dst[1] = v.y; dst[2] = v.z; dst[3] = v.w;
    }
    __syncthreads();

    // --- hoist the 72 weights into registers (fully unrolled -> static indexing) ---
    float wreg[IC][3][3];
    #pragma unroll
    for (int ic = 0; ic < IC; ++ic)
        #pragma unroll
        for (int kh = 0; kh < 3; ++kh)
            #pragma unroll
            for (int kw = 0; kw < 3; ++kw)
                wreg[ic][kh][kw] = wk[ic * 9 + kh * 3 + kw];

    // --- each thread: 1x4 output strip at (oh, ow0..ow0+3) ---
    const int oh   = tid >> 3;          // 0..31
    const int ow0  = (tid & 7) << 2;    // 0,4,...,28
    const int oidx = oh * OW + ow0;     // offset within the oc plane

    const float4 bv = *(const float4*)(bias + oc * OH * OW + oidx);
    float acc0 = bv.x, acc1 = bv.y, acc2 = bv.z, acc3 = bv.w;

    #pragma unroll
    for (int ic = 0; ic < IC; ++ic) {
        #pragma unroll
        for (int kh = 0; kh < 3; ++kh) {
            const float* row = &xs[ic * PLANE + (oh + kh) * XSTR + ow0];
            const float v0 = row[0], v1 = row[1], v2 = row[2];
            const float v3 = row[3], v4 = row[4], v5 = row[5];
            const float w0 = wreg[ic][kh][0];
            const float w1 = wreg[ic][kh][1];
            const float w2 = wreg[ic][kh][2];
            acc0 += v0 * w0 + v1 * w1 + v2 * w2;
            acc1 += v1 * w0 + v2 * w1 + v3 * w2;
            acc2 += v2 * w0 + v3 * w1 + v4 * w2;
            acc3 += v3 * w0 + v4 * w1 + v5 * w2;
        }
    }

    float* op = out + (size_t)(b * OC + oc) * (OH * OW) + oidx;
    *(float4*)op = make_float4(acc0, acc1, acc2, acc3);
}

extern "C" void kernel_launch(void* const* d_in, const int* in_sizes, int n_in,
                              void* d_out, int out_size, void* d_ws, size_t ws_size,
                              hipStream_t stream) {
    const float* x      = (const float*)d_in[0];  // enc_x  [64, 8192]
    const float* weight = (const float*)d_in[1];  // weight [16384, 9248]
    const float* bias   = (const float*)d_in[2];  // bias   [16384]
    // d_in[3] = pad_mat: its effect (zero padding) is realized structurally in LDS.
    float* out = (float*)d_out;                   // [64, 16384]

    conv_toeplitz_kernel<<<dim3(BATCH * OC), dim3(256), 0, stream>>>(x, weight, bias, out);
}

// Round 2
// 10.941 us; speedup vs baseline: 1.1684x; 1.1684x over previous
//
#include <hip/hip_runtime.h>

// Problem geometry (fixed by the reference module config)
#define IC    8
#define OC    16
#define H     32
#define W     32
#define PH    34
#define PW    34
#define OH    32
#define OW    32
#define BATCH 64
#define WCOLS (IC * PH * PW)   // 9248 columns of the Toeplitz weight
#define XSTR  35               // LDS row stride (floats): odd -> <=2-way bank alias (free)
#define PLANE (PH * XSTR)      // 34*35 = 1190 floats per input-channel plane
#define HALO  134              // per-plane halo cells we zero: 2*35 + 2*32

// One block per (batch, oc-pair); 256 threads; each thread computes a 1x4 strip
// for BOTH ocs of the pair (x-window LDS reads shared across the 2 ocs).
__global__ __launch_bounds__(256, 2) void conv_toeplitz_kernel(
    const float* __restrict__ x,       // [B, IC*H*W]
    const float* __restrict__ weight,  // [OC*OH*OW, WCOLS] Toeplitz
    const float* __restrict__ bias,    // [OC*OH*OW]
    float* __restrict__ out)           // [B, OC*OH*OW]
{
    __shared__ float wk[2][IC * 9];     // kernel slices for the oc pair
    __shared__ float xs[IC * PLANE];    // zero-padded input planes

    const int tid = threadIdx.x;
    const int blk = blockIdx.x;
    const int b   = blk >> 3;           // batch index (64)
    const int oc0 = (blk & 7) << 1;     // first oc of the pair

    // --- recover conv kernels from the Toeplitz rows for (oc0, oc0+1) ---
    if (tid < 144) {
        const int os = tid / 72;                // which oc of the pair
        const int k  = tid - os * 72;           // 0..71
        const int ic = k / 9;
        const int r  = k - ic * 9;
        const int kh = r / 3;
        const int kw = r - kh * 3;
        wk[os][k] = weight[(size_t)((oc0 + os) * OH * OW) * WCOLS
                           + (ic * PH + kh) * PW + kw];
    }

    // --- zero ONLY the halo (rows 0/33 full, cols 0/33 of rows 1..32) ---
    for (int i = tid; i < IC * HALO; i += 256) {
        const int plane = i / HALO;
        const int r     = i - plane * HALO;
        int row, col;
        if (r < 35)       { row = 0;          col = r;        }
        else if (r < 70)  { row = 33;         col = r - 35;   }
        else if (r < 102) { row = r - 70 + 1; col = 0;        }
        else              { row = r - 102 + 1; col = 33;      }
        xs[plane * PLANE + row * XSTR + col] = 0.0f;
    }

    // --- stage x[b] into the interior (coalesced float4 global loads) ---
    const float4* xg = (const float4*)(x + (size_t)b * (IC * H * W));
    #pragma unroll
    for (int i = 0; i < 8; ++i) {
        const int k   = tid + i * 256;      // float4 index, 0..2047
        const float4 v = xg[k];
        const int ic  = k >> 8;             // 256 float4 per channel plane
        const int rem = k & 255;
        const int h   = rem >> 3;           // 8 float4 per row
        const int w4  = (rem & 7) << 2;
        float* dst = &xs[ic * PLANE + (h + 1) * XSTR + (w4 + 1)];
        dst[0] = v.x; dst[1] = v.y; dst[2] = v.z; dst[3] = v.w;
    }
    __syncthreads();

    // --- hoist 144 weights into registers (static indexing, no spill at 256 VGPR cap) ---
    float wreg[2][IC * 9];
    #pragma unroll
    for (int o = 0; o < 2; ++o)
        #pragma unroll
        for (int k = 0; k < IC * 9; ++k)
            wreg[o][k] = wk[o][k];

    // --- each thread: 1x4 output strip at (oh, ow0..ow0+3), both ocs ---
    const int oh   = tid >> 3;          // 0..31
    const int ow0  = (tid & 7) << 2;    // 0,4,...,28
    const int oidx = oh * OW + ow0;

    const float4 b0 = *(const float4*)(bias + oc0 * OH * OW + oidx);
    const float4 b1 = *(const float4*)(bias + (oc0 + 1) * OH * OW + oidx);
    float a00 = b0.x, a01 = b0.y, a02 = b0.z, a03 = b0.w;
    float a10 = b1.x, a11 = b1.y, a12 = b1.z, a13 = b1.w;

    #pragma unroll
    for (int ic = 0; ic < IC; ++ic) {
        #pragma unroll
        for (int kh = 0; kh < 3; ++kh) {
            const float* row = &xs[ic * PLANE + (oh + kh) * XSTR + ow0];
            const float v0 = row[0], v1 = row[1], v2 = row[2];
            const float v3 = row[3], v4 = row[4], v5 = row[5];
            const float w00 = wreg[0][ic * 9 + kh * 3];
            const float w01 = wreg[0][ic * 9 + kh * 3 + 1];
            const float w02 = wreg[0][ic * 9 + kh * 3 + 2];
            const float w10 = wreg[1][ic * 9 + kh * 3];
            const float w11 = wreg[1][ic * 9 + kh * 3 + 1];
            const float w12 = wreg[1][ic * 9 + kh * 3 + 2];
            a00 += v0 * w00 + v1 * w01 + v2 * w02;
            a01 += v1 * w00 + v2 * w01 + v3 * w02;
            a02 += v2 * w00 + v3 * w01 + v4 * w02;
            a03 += v3 * w00 + v4 * w01 + v5 * w02;
            a10 += v0 * w10 + v1 * w11 + v2 * w12;
            a11 += v1 * w10 + v2 * w11 + v3 * w12;
            a12 += v2 * w10 + v3 * w11 + v4 * w12;
            a13 += v3 * w10 + v4 * w11 + v5 * w12;
        }
    }

    float* o0 = out + (size_t)(b * OC + oc0) * (OH * OW) + oidx;
    *(float4*)o0 = make_float4(a00, a01, a02, a03);
    float* o1 = o0 + OH * OW;
    *(float4*)o1 = make_float4(a10, a11, a12, a13);
}

extern "C" void kernel_launch(void* const* d_in, const int* in_sizes, int n_in,
                              void* d_out, int out_size, void* d_ws, size_t ws_size,
                              hipStream_t stream) {
    const float* x      = (const float*)d_in[0];  // enc_x  [64, 8192]
    const float* weight = (const float*)d_in[1];  // weight [16384, 9248]
    const float* bias   = (const float*)d_in[2];  // bias   [16384]
    // d_in[3] = pad_mat: realized structurally via the LDS halo.
    float* out = (float*)d_out;                   // [64, 16384]

    conv_toeplitz_kernel<<<dim3(BATCH * (OC / 2)), dim3(256), 0, stream>>>(x, weight, bias, out);
}